// Round 1
// baseline (459.423 us; speedup 1.0000x reference)
//
#include <hip/hip_runtime.h>
#include <math.h>

#define B_N 16384
#define F_N 128
#define H_N 128
#define E_N 32
#define ROWS (H_N + 1)   // 129 prefix rows per feature

// ---------------------------------------------------------------------------
// Kernel A: per-feature table build.
// For feature f, each hidden unit h contributes relu(x*w1+b1)*w2[h,:].
// relu is active iff x > t (w1>0) or x < t (w1<0), t = -b1/w1.
// Sort thresholds ascending; A[r] = sum over active-set(w1*w2) when r
// thresholds are below x; C[r] likewise with b1*w2 (+b2 folded in).
// ---------------------------------------------------------------------------
__global__ __launch_bounds__(128) void build_tables(
    const float* __restrict__ w1, const float* __restrict__ b1,
    const float* __restrict__ w2, const float* __restrict__ b2,
    float* __restrict__ ts_out, float* __restrict__ A, float* __restrict__ C)
{
    __shared__ float w1s[H_N], b1s[H_N], ts[H_N];
    __shared__ int   hidx[H_N];
    const int f   = blockIdx.x;
    const int tid = threadIdx.x;

    float w1v = w1[f * H_N + tid];
    float b1v = b1[f * H_N + tid];
    w1s[tid] = w1v;
    b1s[tid] = b1v;
    // w1==0: constant contribution (handled in base), never crossed -> +inf
    ts[tid]   = (w1v != 0.0f) ? (-b1v / w1v) : INFINITY;
    hidx[tid] = tid;
    __syncthreads();

    // bitonic sort, ascending by ts, payload hidx
    for (int k = 2; k <= H_N; k <<= 1) {
        for (int j = k >> 1; j > 0; j >>= 1) {
            int ixj = tid ^ j;
            if (ixj > tid) {
                float a = ts[tid], bv = ts[ixj];
                bool up = ((tid & k) == 0);
                bool sw = up ? (a > bv) : (a < bv);
                if (sw) {
                    int ia = hidx[tid];
                    ts[tid] = bv; ts[ixj] = a;
                    hidx[tid] = hidx[ixj]; hidx[ixj] = ia;
                }
            }
            __syncthreads();
        }
    }

    ts_out[f * H_N + tid] = ts[tid];

    if (tid < E_N) {
        const float* w2f = w2 + (size_t)f * H_N * E_N;
        // base state at x = -inf: all w1<0 units active; w1==0&&b1>0 constant
        float accA = 0.f, accC = 0.f;
        for (int h = 0; h < H_N; ++h) {
            float w1h = w1s[h], b1h = b1s[h];
            float w2v = w2f[h * E_N + tid];
            if (w1h < 0.f) {
                accA = fmaf(w1h, w2v, accA);
                accC = fmaf(b1h, w2v, accC);
            } else if (w1h == 0.f && b1h > 0.f) {
                accC = fmaf(b1h, w2v, accC);
            }
        }
        accC += b2[f * E_N + tid];
        const size_t base = (size_t)f * ROWS * E_N;
        A[base + tid] = accA;
        C[base + tid] = accC;
        // crossing sorted threshold j: w1>0 activates (+), w1<0 deactivates (-)
        for (int j = 0; j < H_N; ++j) {
            int   p   = hidx[j];
            float w1h = w1s[p], b1h = b1s[p];
            float w2v = w2f[p * E_N + tid];
            float s   = (w1h > 0.f) ? 1.f : ((w1h < 0.f) ? -1.f : 0.f);
            accA = fmaf(s * w1h, w2v, accA);
            accC = fmaf(s * b1h, w2v, accC);
            A[base + (size_t)(j + 1) * E_N + tid] = accA;
            C[base + (size_t)(j + 1) * E_N + tid] = accC;
        }
    }
}

// ---------------------------------------------------------------------------
// Kernel B: out[b,f,e] = x[b,f] * A[f,r,e] + C[f,r,e],
// r = lower_bound(sorted thresholds of f, x). Write-bandwidth bound.
// Block: 64 features x 32 batch rows, 256 threads = 64 fl x 4 e-octets.
// ---------------------------------------------------------------------------
#define NB 32
#define FH 64

__global__ __launch_bounds__(256) void apply_tables(
    const float* __restrict__ x, const float* __restrict__ ts,
    const float* __restrict__ A, const float* __restrict__ C,
    float* __restrict__ out)
{
    __shared__ float lds_t[FH * ROWS];   // 64*129*4 = 33 KB (pad kills conflicts)
    __shared__ float xs[NB * FH];        // 8 KB

    const int tid = threadIdx.x;
    const int b0  = blockIdx.x * NB;
    const int f0  = blockIdx.y * FH;

    // stage sorted thresholds: FH*H_N = 8192 floats, float4 coalesced
    {
        const float4* src = (const float4*)(ts + (size_t)f0 * H_N);
        #pragma unroll
        for (int it = 0; it < (FH * H_N / 4) / 256; ++it) {   // 8
            int    vi  = it * 256 + tid;
            float4 v   = src[vi];
            int    idx = vi * 4;
            int    fl  = idx >> 7;
            int    j   = idx & 127;
            float* dst = &lds_t[fl * ROWS + j];
            dst[0] = v.x; dst[1] = v.y; dst[2] = v.z; dst[3] = v.w;
        }
    }
    // stage x tile: NB x FH floats
    {
        #pragma unroll
        for (int it = 0; it < (NB * FH / 4) / 256; ++it) {    // 2
            int vi  = it * 256 + tid;
            int idx = vi * 4;
            int bl  = idx >> 6;
            int fl  = idx & 63;
            float4 v = *(const float4*)(x + (size_t)(b0 + bl) * F_N + f0 + fl);
            *(float4*)(&xs[bl * FH + fl]) = v;
        }
    }
    __syncthreads();

    const int fl = tid >> 2;        // 0..63
    const int q  = tid & 3;         // e-octet
    const int fg = f0 + fl;
    const float* tloc     = &lds_t[fl * ROWS];
    const size_t tab_base = (size_t)fg * ROWS * E_N + q * 8;
    const size_t out_base = (size_t)b0 * (F_N * E_N) + (size_t)fg * E_N + q * 8;

    for (int bl = 0; bl < NB; ++bl) {
        float xv = xs[bl * FH + fl];
        // lower_bound over 128 sorted thresholds -> r in [0,128]
        int lo = 0, hi = H_N;
        #pragma unroll
        for (int s = 0; s < 7; ++s) {
            int  mid = (lo + hi) >> 1;
            bool lt  = tloc[mid] < xv;
            lo = lt ? mid + 1 : lo;
            hi = lt ? hi : mid;
        }
        const size_t row = tab_base + (size_t)lo * E_N;
        const float4* a4 = (const float4*)(A + row);
        const float4* c4 = (const float4*)(C + row);
        float4 a0 = a4[0], a1 = a4[1];
        float4 c0 = c4[0], c1 = c4[1];
        float4 o0, o1;
        o0.x = fmaf(xv, a0.x, c0.x); o0.y = fmaf(xv, a0.y, c0.y);
        o0.z = fmaf(xv, a0.z, c0.z); o0.w = fmaf(xv, a0.w, c0.w);
        o1.x = fmaf(xv, a1.x, c1.x); o1.y = fmaf(xv, a1.y, c1.y);
        o1.z = fmaf(xv, a1.z, c1.z); o1.w = fmaf(xv, a1.w, c1.w);
        float4* op = (float4*)(out + out_base + (size_t)bl * (F_N * E_N));
        op[0] = o0;
        op[1] = o1;
    }
}

// ---------------------------------------------------------------------------
// Fallback (only if d_ws is too small): direct fp32 compute, ~VALU-bound.
// ---------------------------------------------------------------------------
__global__ __launch_bounds__(256) void direct_kernel(
    const float* __restrict__ x, const float* __restrict__ w1,
    const float* __restrict__ b1, const float* __restrict__ w2,
    const float* __restrict__ b2, float* __restrict__ out)
{
    __shared__ float w1s[H_N], b1s[H_N], b2s[E_N];
    __shared__ float w2s[H_N * E_N];
    const int f   = blockIdx.y;
    const int tid = threadIdx.x;
    if (tid < H_N) { w1s[tid] = w1[f * H_N + tid]; b1s[tid] = b1[f * H_N + tid]; }
    for (int i = tid; i < H_N * E_N; i += 256) w2s[i] = w2[(size_t)f * H_N * E_N + i];
    if (tid < E_N) b2s[tid] = b2[f * E_N + tid];
    __syncthreads();

    const int b  = blockIdx.x * 256 + tid;
    float xv = x[(size_t)b * F_N + f];
    float acc[E_N];
    #pragma unroll
    for (int e = 0; e < E_N; ++e) acc[e] = b2s[e];
    for (int h = 0; h < H_N; ++h) {
        float hv = fmaxf(fmaf(xv, w1s[h], b1s[h]), 0.f);
        #pragma unroll
        for (int e = 0; e < E_N; ++e) acc[e] = fmaf(hv, w2s[h * E_N + e], acc[e]);
    }
    float* op = out + (size_t)b * (F_N * E_N) + (size_t)f * E_N;
    #pragma unroll
    for (int e = 0; e < E_N; e += 4)
        *(float4*)(op + e) = make_float4(acc[e], acc[e + 1], acc[e + 2], acc[e + 3]);
}

extern "C" void kernel_launch(void* const* d_in, const int* in_sizes, int n_in,
                              void* d_out, int out_size, void* d_ws, size_t ws_size,
                              hipStream_t stream) {
    const float* x  = (const float*)d_in[0];
    const float* w1 = (const float*)d_in[1];
    const float* b1 = (const float*)d_in[2];
    const float* w2 = (const float*)d_in[3];
    const float* b2 = (const float*)d_in[4];
    float* out = (float*)d_out;

    const size_t n_ts  = (size_t)F_N * H_N;
    const size_t n_tab = (size_t)F_N * ROWS * E_N;
    const size_t need  = (n_ts + 2 * n_tab) * sizeof(float);

    if (ws_size >= need) {
        float* ts = (float*)d_ws;
        float* A  = ts + n_ts;
        float* C  = A + n_tab;
        build_tables<<<dim3(F_N), dim3(128), 0, stream>>>(w1, b1, w2, b2, ts, A, C);
        apply_tables<<<dim3(B_N / NB, F_N / FH), dim3(256), 0, stream>>>(x, ts, A, C, out);
    } else {
        direct_kernel<<<dim3(B_N / 256, F_N), dim3(256), 0, stream>>>(x, w1, b1, w2, b2, out);
    }
}

// Round 2
// 334.148 us; speedup vs baseline: 1.3749x; 1.3749x over previous
//
#include <hip/hip_runtime.h>
#include <math.h>

#define B_N 16384
#define F_N 128
#define H_N 128
#define E_N 32
#define ROWS (H_N + 1)   // 129 prefix rows per feature
// Interleaved table: tab[f][row][0..31] = A, tab[f][row][32..63] = C  (256 B/row)

// ---------------------------------------------------------------------------
// Kernel A: per-feature table build. relu(x*w1+b1) is linear in x with one
// breakpoint t = -b1/w1. Sort thresholds; prefix tables over the active set.
// v2: w2 staged to LDS, deltas computed by all 128 threads in parallel,
// only the final 128-step prefix is serial (LDS-resident, cheap).
// ---------------------------------------------------------------------------
__global__ __launch_bounds__(128) void build_tables(
    const float* __restrict__ w1, const float* __restrict__ b1,
    const float* __restrict__ w2, const float* __restrict__ b2,
    float* __restrict__ ts_out, float* __restrict__ tab)
{
    __shared__ float w1s[H_N], b1s[H_N], ts[H_N];
    __shared__ int   hidx[H_N];
    __shared__ float w2s[H_N * E_N];   // 16 KB
    __shared__ float dA[H_N * E_N];    // 16 KB
    __shared__ float dC[H_N * E_N];    // 16 KB
    __shared__ float baseA[4 * E_N], baseC[4 * E_N];

    const int f   = blockIdx.x;
    const int tid = threadIdx.x;

    float w1v = w1[f * H_N + tid];
    float b1v = b1[f * H_N + tid];
    w1s[tid] = w1v;
    b1s[tid] = b1v;
    ts[tid]   = (w1v != 0.0f) ? (-b1v / w1v) : INFINITY;
    hidx[tid] = tid;

    // stage w2[f]: 4096 floats = 1024 float4, 8 per thread, coalesced
    {
        const float4* src = (const float4*)(w2 + (size_t)f * H_N * E_N);
        float4*       dst = (float4*)w2s;
        #pragma unroll
        for (int it = 0; it < 8; ++it) dst[it * 128 + tid] = src[it * 128 + tid];
    }
    __syncthreads();

    // bitonic sort ascending by ts, payload hidx
    for (int k = 2; k <= H_N; k <<= 1) {
        for (int j = k >> 1; j > 0; j >>= 1) {
            int ixj = tid ^ j;
            if (ixj > tid) {
                float a = ts[tid], bv = ts[ixj];
                bool up = ((tid & k) == 0);
                bool sw = up ? (a > bv) : (a < bv);
                if (sw) {
                    int ia = hidx[tid];
                    ts[tid] = bv; ts[ixj] = a;
                    hidx[tid] = hidx[ixj]; hidx[ixj] = ia;
                }
            }
            __syncthreads();
        }
    }

    ts_out[f * H_N + tid] = ts[tid];

    const int e = tid & 31;    // embedding lane
    const int g = tid >> 5;    // 0..3 group

    // crossing deltas, all threads: group g handles sorted positions g*32..+31
    #pragma unroll 4
    for (int jj = 0; jj < 32; ++jj) {
        int   j   = g * 32 + jj;
        int   p   = hidx[j];
        float w1h = w1s[p], b1h = b1s[p];
        float w2v = w2s[p * E_N + e];
        float s   = (w1h > 0.f) ? 1.f : ((w1h < 0.f) ? -1.f : 0.f);
        dA[j * E_N + e] = s * w1h * w2v;
        dC[j * E_N + e] = s * b1h * w2v;
    }
    // base state at x=-inf: group-partial sums
    {
        float pA = 0.f, pC = 0.f;
        #pragma unroll 4
        for (int hh = 0; hh < 32; ++hh) {
            int   h   = g * 32 + hh;
            float w1h = w1s[h], b1h = b1s[h];
            float w2v = w2s[h * E_N + e];
            if (w1h < 0.f) {
                pA = fmaf(w1h, w2v, pA);
                pC = fmaf(b1h, w2v, pC);
            } else if (w1h == 0.f && b1h > 0.f) {
                pC = fmaf(b1h, w2v, pC);
            }
        }
        baseA[g * E_N + e] = pA;
        baseC[g * E_N + e] = pC;
    }
    __syncthreads();

    // serial prefix over 129 rows, 32 lanes (one per e); all data LDS-resident
    if (tid < E_N) {
        float accA = baseA[e] + baseA[E_N + e] + baseA[2 * E_N + e] + baseA[3 * E_N + e];
        float accC = baseC[e] + baseC[E_N + e] + baseC[2 * E_N + e] + baseC[3 * E_N + e];
        accC += b2[f * E_N + e];
        const size_t base = (size_t)f * ROWS * 64;
        tab[base + e]        = accA;
        tab[base + 32 + e]   = accC;
        for (int j = 0; j < H_N; ++j) {
            accA += dA[j * E_N + e];
            accC += dC[j * E_N + e];
            tab[base + (size_t)(j + 1) * 64 + e]      = accA;
            tab[base + (size_t)(j + 1) * 64 + 32 + e] = accC;
        }
    }
}

// ---------------------------------------------------------------------------
// Kernel B: out[b,f,e] = x*A[f,r,e] + C[f,r,e], r = lower_bound(ts_f, x).
// v2: 8-wide ILP batches (step-major binary search, then batched gathers),
// smaller LDS (24.6 KB -> 6 blocks/CU), interleaved A/C table rows.
// ---------------------------------------------------------------------------
#define FH 32   // features per block
#define NB 64   // batch rows per block
#define CH 8    // ILP chunk

__global__ __launch_bounds__(256) void apply_tables(
    const float* __restrict__ x, const float* __restrict__ ts,
    const float* __restrict__ tab, float* __restrict__ out)
{
    __shared__ float lds_t[FH * ROWS];   // 32*129*4 = 16.5 KB
    __shared__ float xs[NB * FH];        // 8 KB

    const int tid = threadIdx.x;
    const int b0  = blockIdx.x * NB;
    const int f0  = blockIdx.y * FH;

    // stage sorted thresholds: FH*128 = 4096 floats = 1024 float4
    {
        const float4* src = (const float4*)(ts + (size_t)f0 * H_N);
        #pragma unroll
        for (int it = 0; it < (FH * H_N / 4) / 256; ++it) {   // 4
            int    vi  = it * 256 + tid;
            float4 v   = src[vi];
            int    idx = vi * 4;
            int    fl  = idx >> 7;       // /128
            int    j   = idx & 127;
            float* dst = &lds_t[fl * ROWS + j];
            dst[0] = v.x; dst[1] = v.y; dst[2] = v.z; dst[3] = v.w;
        }
    }
    // stage x tile: NB x FH = 2048 floats = 512 float4
    {
        #pragma unroll
        for (int it = 0; it < (NB * FH / 4) / 256; ++it) {    // 2
            int vi = it * 256 + tid;
            int bl = vi >> 3;            // 8 float4 per row of 32
            int fq = (vi & 7) * 4;
            float4 v = *(const float4*)(x + (size_t)(b0 + bl) * F_N + f0 + fq);
            *(float4*)(&xs[bl * FH + fq]) = v;
        }
    }
    __syncthreads();

    const int fl = tid >> 3;        // 0..31 feature lane
    const int eq = tid & 7;         // 0..7 e-quad
    const int fg = f0 + fl;
    const float* tloc     = &lds_t[fl * ROWS];
    const size_t tab_base = (size_t)fg * ROWS * 64 + eq * 4;
    const size_t out_base = (size_t)b0 * (F_N * E_N) + (size_t)fg * E_N + eq * 4;

    for (int c = 0; c < NB / CH; ++c) {
        float xv[CH];
        int   lo[CH], hi[CH];
        #pragma unroll
        for (int j = 0; j < CH; ++j) {
            xv[j] = xs[(c * CH + j) * FH + fl];
            lo[j] = 0;
            hi[j] = H_N;
        }
        // step-major: 8 independent LDS reads in flight per step
        #pragma unroll
        for (int s = 0; s < 7; ++s) {
            #pragma unroll
            for (int j = 0; j < CH; ++j) {
                int  mid = (lo[j] + hi[j]) >> 1;
                bool lt  = tloc[mid] < xv[j];
                lo[j] = lt ? mid + 1 : lo[j];
                hi[j] = lt ? hi[j] : mid;
            }
        }
        // batched gathers + FMA + coalesced stores (8 independent streams)
        #pragma unroll
        for (int j = 0; j < CH; ++j) {
            const float* row = tab + tab_base + (size_t)lo[j] * 64;
            float4 a4 = *(const float4*)(row);
            float4 c4 = *(const float4*)(row + 32);
            float  xj = xv[j];
            float4 o;
            o.x = fmaf(xj, a4.x, c4.x);
            o.y = fmaf(xj, a4.y, c4.y);
            o.z = fmaf(xj, a4.z, c4.z);
            o.w = fmaf(xj, a4.w, c4.w);
            *(float4*)(out + out_base + (size_t)(c * CH + j) * (F_N * E_N)) = o;
        }
    }
}

// ---------------------------------------------------------------------------
// Fallback (only if d_ws is too small): direct fp32 compute.
// ---------------------------------------------------------------------------
__global__ __launch_bounds__(256) void direct_kernel(
    const float* __restrict__ x, const float* __restrict__ w1,
    const float* __restrict__ b1, const float* __restrict__ w2,
    const float* __restrict__ b2, float* __restrict__ out)
{
    __shared__ float w1s[H_N], b1s[H_N], b2s[E_N];
    __shared__ float w2s[H_N * E_N];
    const int f   = blockIdx.y;
    const int tid = threadIdx.x;
    if (tid < H_N) { w1s[tid] = w1[f * H_N + tid]; b1s[tid] = b1[f * H_N + tid]; }
    for (int i = tid; i < H_N * E_N; i += 256) w2s[i] = w2[(size_t)f * H_N * E_N + i];
    if (tid < E_N) b2s[tid] = b2[f * E_N + tid];
    __syncthreads();

    const int b  = blockIdx.x * 256 + tid;
    float xv = x[(size_t)b * F_N + f];
    float acc[E_N];
    #pragma unroll
    for (int e = 0; e < E_N; ++e) acc[e] = b2s[e];
    for (int h = 0; h < H_N; ++h) {
        float hv = fmaxf(fmaf(xv, w1s[h], b1s[h]), 0.f);
        #pragma unroll
        for (int e = 0; e < E_N; ++e) acc[e] = fmaf(hv, w2s[h * E_N + e], acc[e]);
    }
    float* op = out + (size_t)b * (F_N * E_N) + (size_t)f * E_N;
    #pragma unroll
    for (int e = 0; e < E_N; e += 4)
        *(float4*)(op + e) = make_float4(acc[e], acc[e + 1], acc[e + 2], acc[e + 3]);
}

extern "C" void kernel_launch(void* const* d_in, const int* in_sizes, int n_in,
                              void* d_out, int out_size, void* d_ws, size_t ws_size,
                              hipStream_t stream) {
    const float* x  = (const float*)d_in[0];
    const float* w1 = (const float*)d_in[1];
    const float* b1 = (const float*)d_in[2];
    const float* w2 = (const float*)d_in[3];
    const float* b2 = (const float*)d_in[4];
    float* out = (float*)d_out;

    const size_t n_ts  = (size_t)F_N * H_N;
    const size_t n_tab = (size_t)F_N * ROWS * 64;
    const size_t need  = (n_ts + n_tab) * sizeof(float);

    if (ws_size >= need) {
        float* ts  = (float*)d_ws;
        float* tab = ts + n_ts;
        build_tables<<<dim3(F_N), dim3(128), 0, stream>>>(w1, b1, w2, b2, ts, tab);
        apply_tables<<<dim3(B_N / NB, F_N / FH), dim3(256), 0, stream>>>(x, ts, tab, out);
    } else {
        direct_kernel<<<dim3(B_N / 256, F_N), dim3(256), 0, stream>>>(x, w1, b1, w2, b2, out);
    }
}